// Round 1
// 348.042 us; speedup vs baseline: 1.0528x; 1.0528x over previous
//
#include <hip/hip_runtime.h>
#include <cstdint>
#include <cstddef>

#define BDIM 8192
#define DDIM 256
#define NT 64            // 8192 / 128 tiles per side
#define NTILES 2080      // NT*(NT+1)/2 upper-tri tiles
#define LAMBDA_REG 0.1f

typedef __bf16 bf16x8 __attribute__((ext_vector_type(8)));
typedef __bf16 bf16x4 __attribute__((ext_vector_type(4)));
typedef float  f32x4  __attribute__((ext_vector_type(4)));

// ---------------- Kernel 1: row-normalize fp32 -> bf16 ----------------
// One wave per row (256 cols -> 1 float4 per lane). Block = 4 rows.
__global__ __launch_bounds__(256) void normalize_k(const float* __restrict__ emb,
                                                   __bf16* __restrict__ en) {
    int row  = (blockIdx.x << 2) + (threadIdx.x >> 6);
    int lane = threadIdx.x & 63;
    float4 v = ((const float4*)(emb + (size_t)row * DDIM))[lane];
    float ss = v.x * v.x + v.y * v.y + v.z * v.z + v.w * v.w;
#pragma unroll
    for (int off = 32; off; off >>= 1) ss += __shfl_down(ss, off, 64);
    ss = __shfl(ss, 0, 64);
    float r = 1.0f / fmaxf(sqrtf(ss), 1e-8f);
    bf16x4 o;
    o.x = (__bf16)(v.x * r);
    o.y = (__bf16)(v.y * r);
    o.z = (__bf16)(v.z * r);
    o.w = (__bf16)(v.w * r);
    ((bf16x4*)(en + (size_t)row * DDIM))[lane] = o;
}

// ---------------- Kernel 2: per-tile cos + |T - cos| reduction ----------------
// One block per upper-triangular 128x128 tile. 256 threads = 4 waves (2x2 of 64x64).
// BK=32, 8 K-steps over D=256. m97-style global_load_lds width-16 staging.
// R2 lesson: no nontemporal loads on ts (nt bypass doubled the stream time).
// R4 lesson: do NOT stage ts into LDS inside the K-loop — the step-end barrier
// drains vmcnt(0) so the ts queue chains into every K-step, and 80 KB LDS
// halves occupancy; inter-block phase stagger already overlaps the ts stream.
// R5 (this round): SWAPPED MFMA OPERANDS — acc[mi][ni] = mfma(bfr[ni], af[mi], .)
// puts the accumulator 'reg' axis on the COLUMN of the cos tile:
//   C[rowbase+wm*64+mi*16+(lane&15)][colbase+wn*64+ni*16+((lane>>4)<<2)+r]
// so each lane's 4 acc values per (mi,ni) match 4 CONSECUTIVE ts columns ->
// the ts read becomes 16 x global_load_dwordx4 per thread (4 base pointers +
// 64B immediate offsets) instead of 64 scalar dword loads + 64 addr calcs.
#define TRIOFF(r) ((r) * NT - ((r) * ((r) - 1)) / 2)

__global__ __launch_bounds__(256) void pair_loss_k(const __bf16* __restrict__ en,
                                                   const float* __restrict__ ts,
                                                   float* __restrict__ partials) {
    __shared__ __align__(16) __bf16 As[128 * 32];
    __shared__ __align__(16) __bf16 Bs[128 * 32];
    __shared__ float wsum[4];

    const int t = blockIdx.x;
    // map linear tile id -> (bi, bj) with bi <= bj
    int bi = (int)((2.0f * NT + 1.0f -
                    sqrtf((2.0f * NT + 1.0f) * (2.0f * NT + 1.0f) - 8.0f * (float)t)) * 0.5f);
    if (bi < 0) bi = 0;
    while (TRIOFF(bi + 1) <= t) ++bi;
    while (TRIOFF(bi) > t) --bi;
    const int bj = bi + (t - TRIOFF(bi));

    const int tid  = threadIdx.x;
    const int w    = tid >> 6;
    const int lane = tid & 63;
    const int wm   = w >> 1;   // wave row (0..1) of 64
    const int wn   = w & 1;    // wave col (0..1) of 64

    const int rowbase = bi * 128;
    const int colbase = bj * 128;

    f32x4 acc[4][4];
    const f32x4 zero = {0.f, 0.f, 0.f, 0.f};
#pragma unroll
    for (int mi = 0; mi < 4; ++mi)
#pragma unroll
        for (int ni = 0; ni < 4; ++ni) acc[mi][ni] = zero;

    // staging: thread tid stages 16B = 8 bf16; row = tid/4, col-group = (tid%4)*8
    const int srow = tid >> 2;
    const int scol = (tid & 3) << 3;
    const int khalf = (lane >> 4) << 3;  // 0,8,16,24 (k offset of this lane's frag)
    const int r16   = lane & 15;

#pragma unroll
    for (int kk = 0; kk < DDIM / 32; ++kk) {
        const int k0 = kk * 32;
        const __bf16* ga0 = en + (size_t)(rowbase + srow)      * DDIM + k0 + scol;
        const __bf16* ga1 = en + (size_t)(rowbase + 64 + srow) * DDIM + k0 + scol;
        const __bf16* gb0 = en + (size_t)(colbase + srow)      * DDIM + k0 + scol;
        const __bf16* gb1 = en + (size_t)(colbase + 64 + srow) * DDIM + k0 + scol;
        __builtin_amdgcn_global_load_lds((const __attribute__((address_space(1))) void*)ga0,
                                         (__attribute__((address_space(3))) void*)(&As[tid * 8]),
                                         16, 0, 0);
        __builtin_amdgcn_global_load_lds((const __attribute__((address_space(1))) void*)ga1,
                                         (__attribute__((address_space(3))) void*)(&As[2048 + tid * 8]),
                                         16, 0, 0);
        __builtin_amdgcn_global_load_lds((const __attribute__((address_space(1))) void*)gb0,
                                         (__attribute__((address_space(3))) void*)(&Bs[tid * 8]),
                                         16, 0, 0);
        __builtin_amdgcn_global_load_lds((const __attribute__((address_space(1))) void*)gb1,
                                         (__attribute__((address_space(3))) void*)(&Bs[2048 + tid * 8]),
                                         16, 0, 0);
        __syncthreads();

        bf16x8 af[4], bfr[4];
#pragma unroll
        for (int mi = 0; mi < 4; ++mi)
            af[mi] = *(const bf16x8*)&As[(wm * 64 + mi * 16 + r16) * 32 + khalf];
#pragma unroll
        for (int ni = 0; ni < 4; ++ni)
            bfr[ni] = *(const bf16x8*)&Bs[(wn * 64 + ni * 16 + r16) * 32 + khalf];
        // R5: operands swapped (bfr first) -> transposed D-axis assignment.
#pragma unroll
        for (int mi = 0; mi < 4; ++mi)
#pragma unroll
            for (int ni = 0; ni < 4; ++ni)
                acc[mi][ni] = __builtin_amdgcn_mfma_f32_16x16x32_bf16(bfr[ni], af[mi],
                                                                      acc[mi][ni], 0, 0, 0);
        __syncthreads();
    }

    // epilogue: |T - cos| with i<j mask (only diagonal tiles need the compare).
    // acc[mi][ni][r] = cos[grB + mi*16][gcB + ni*16 + r]  (see R5 note above).
    // 4 independent accumulators (per mi) break the serial fadd chain for ILP.
    float sacc[4] = {0.f, 0.f, 0.f, 0.f};
    const int grB = rowbase + wm * 64 + (lane & 15);
    const int gcB = colbase + wn * 64 + ((lane >> 4) << 2);
    if (bi != bj) {
#pragma unroll
        for (int mi = 0; mi < 4; ++mi) {
            const float* rowp = ts + (size_t)(grB + mi * 16) * BDIM + gcB;
#pragma unroll
            for (int ni = 0; ni < 4; ++ni) {
                const f32x4 tv = *(const f32x4*)(rowp + ni * 16);
                const f32x4 a  = acc[mi][ni];
                sacc[mi] += fabsf(tv[0] - a[0]) + fabsf(tv[1] - a[1]) +
                            fabsf(tv[2] - a[2]) + fabsf(tv[3] - a[3]);
            }
        }
    } else {
#pragma unroll
        for (int mi = 0; mi < 4; ++mi) {
            const int gr = grB + mi * 16;
            const float* rowp = ts + (size_t)gr * BDIM + gcB;
#pragma unroll
            for (int ni = 0; ni < 4; ++ni) {
                const int gc0 = gcB + ni * 16;
                const f32x4 tv = *(const f32x4*)(rowp + ni * 16);
                const f32x4 a  = acc[mi][ni];
#pragma unroll
                for (int r = 0; r < 4; ++r)
                    if (gc0 + r > gr) sacc[mi] += fabsf(tv[r] - a[r]);
            }
        }
    }
    float s = (sacc[0] + sacc[1]) + (sacc[2] + sacc[3]);

    // wave reduce then block reduce -> one partial per tile
#pragma unroll
    for (int off = 32; off; off >>= 1) s += __shfl_down(s, off, 64);
    if (lane == 0) wsum[w] = s;
    __syncthreads();
    if (tid == 0) partials[t] = wsum[0] + wsum[1] + wsum[2] + wsum[3];
}

// ---------------- Kernel 3: final reduction ----------------
__global__ __launch_bounds__(256) void finish_k(const float* __restrict__ partials,
                                                float* __restrict__ out) {
    float s = 0.f;
    for (int i = threadIdx.x; i < NTILES; i += 256) s += partials[i];
    __shared__ float sm[4];
    const int w = threadIdx.x >> 6, lane = threadIdx.x & 63;
#pragma unroll
    for (int off = 32; off; off >>= 1) s += __shfl_down(s, off, 64);
    if (lane == 0) sm[w] = s;
    __syncthreads();
    if (threadIdx.x == 0) {
        const float count = (float)BDIM * (float)(BDIM - 1) * 0.5f;
        out[0] = LAMBDA_REG * (sm[0] + sm[1] + sm[2] + sm[3]) / count;
    }
}

extern "C" void kernel_launch(void* const* d_in, const int* in_sizes, int n_in,
                              void* d_out, int out_size, void* d_ws, size_t ws_size,
                              hipStream_t stream) {
    const float* emb = (const float*)d_in[0];   // [8192, 256] fp32
    const float* ts  = (const float*)d_in[1];   // [8192, 8192] fp32
    __bf16* en       = (__bf16*)d_ws;                                   // 4 MB
    float* partials  = (float*)((char*)d_ws + (size_t)BDIM * DDIM * 2); // 2080 floats

    normalize_k<<<BDIM / 4, 256, 0, stream>>>(emb, en);
    pair_loss_k<<<NTILES, 256, 0, stream>>>(en, ts, partials);
    finish_k<<<1, 256, 0, stream>>>(partials, (float*)d_out);
}